// Round 12
// baseline (26.323 us; speedup 1.0000x reference)
//
#include <hip/hip_runtime.h>
#include <cstdint>

namespace {

constexpr int N    = 20000;   // nodes
constexpr int D    = 128;     // feature dim
constexpr int DEG  = 32;      // neighbors per node
constexpr int BB   = 1024;    // batch
constexpr int T    = 8;       // walk_times
constexpr int NC   = (N + 15) / 16;  // 1250 combined-mask words (2 bits/node)
constexpr int MAXC = 384;     // list bound per row (true max ~292)

__device__ __forceinline__ uint32_t rotl32(uint32_t x, int n) {
  return (x << n) | (x >> (32 - n));
}

// Threefry-2x32, 20 rounds (Random123 / JAX threefry2x32_p).
__device__ __forceinline__ void threefry2x32(uint32_t k0, uint32_t k1,
                                             uint32_t x0, uint32_t x1,
                                             uint32_t& o0, uint32_t& o1) {
  const uint32_t ks2 = k0 ^ k1 ^ 0x1BD11BDAu;
  x0 += k0; x1 += k1;
#define TF_ROUND(r) { x0 += x1; x1 = rotl32(x1, (r)); x1 ^= x0; }
  TF_ROUND(13) TF_ROUND(15) TF_ROUND(26) TF_ROUND(6)
  x0 += k1;  x1 += ks2 + 1u;
  TF_ROUND(17) TF_ROUND(29) TF_ROUND(16) TF_ROUND(24)
  x0 += ks2; x1 += k0 + 2u;
  TF_ROUND(13) TF_ROUND(15) TF_ROUND(26) TF_ROUND(6)
  x0 += k0;  x1 += k1 + 3u;
  TF_ROUND(17) TF_ROUND(29) TF_ROUND(16) TF_ROUND(24)
  x0 += k1;  x1 += ks2 + 4u;
  TF_ROUND(13) TF_ROUND(15) TF_ROUND(26) TF_ROUND(6)
  x0 += ks2; x1 += k0 + 5u;
#undef TF_ROUND
  o0 = x0; o1 = x1;
}

__device__ __forceinline__ uint32_t rbits(uint32_t k0, uint32_t k1, uint32_t j) {
  uint32_t o0, o1;
  threefry2x32(k0, k1, 0u, j, o0, o1);
  return o0 ^ o1;
}

// Exact jax.random.gumbel f32 pipeline (step 0 only).
__device__ __forceinline__ float gumbel_f32(uint32_t bits) {
  const uint32_t mant = bits >> 9;
  const float u = (mant == 0u) ? 1.17549435e-38f
                               : (__uint_as_float(0x3F800000u | mant) - 1.0f);
  const float inner = -(float)log((double)u);
  return -(float)log((double)inner);
}

// Monotone f32 -> u32 map (finite floats).
__device__ __forceinline__ uint32_t f2ord(float f) {
  const uint32_t b = __float_as_uint(f);
  return (b & 0x80000000u) ? ~b : (b | 0x80000000u);
}

template <int CTRL>
__device__ __forceinline__ uint32_t dppmov(uint32_t v) {
  return (uint32_t)__builtin_amdgcn_update_dpp((int)v, (int)v, CTRL, 0xF, 0xF, false);
}

// Per-HALF (32-lane) max of packed (hi:lo); result broadcast within each half.
// row_shr:1/2/4/8 -> row maxima at lanes 15/31/47/63; bcast15 merges row pairs
// within each half (lane31 = halfA max, lane63 = halfB max). No cross-half level.
__device__ __forceinline__ void wave_max64_half(uint32_t& hi, uint32_t& lo, int half) {
#define RL(CTRL) { const uint32_t oh = dppmov<CTRL>(hi), ol = dppmov<CTRL>(lo); \
    if (oh > hi || (oh == hi && ol > lo)) { hi = oh; lo = ol; } }
  RL(0x111) RL(0x112) RL(0x114) RL(0x118) RL(0x142)
#undef RL
  const uint32_t hA = (uint32_t)__builtin_amdgcn_readlane((int)hi, 31);
  const uint32_t lA = (uint32_t)__builtin_amdgcn_readlane((int)lo, 31);
  const uint32_t hB = (uint32_t)__builtin_amdgcn_readlane((int)hi, 63);
  const uint32_t lB = (uint32_t)__builtin_amdgcn_readlane((int)lo, 63);
  hi = half ? hB : hA; lo = half ? lB : lA;
}

// combined mask helpers: word holds 16 nodes x {cand bit, chosen bit}
__device__ __forceinline__ uint32_t cwd(int n)  { return (uint32_t)n >> 4; }
__device__ __forceinline__ uint32_t cbit(int n) { return 1u << (((uint32_t)n & 15u) << 1); }
// chosen bit = cbit << 1

__global__ __launch_bounds__(64)
void walk_kernel(const float* __restrict__ features,
                 const float* __restrict__ W,
                 const float* __restrict__ bptr,
                 const int*   __restrict__ neighbors,
                 const int*   __restrict__ train_index,
                 int* __restrict__ out)
{
  // TWO rows per wave: lanes 0-31 = row bid, lanes 32-63 = row bid + BB/2.
  __shared__ __align__(8) uint32_t comb[2][NC];  // per-row cand/chosen bits
  __shared__ int      lst[2][MAXC];              // per-row candidate list
  __shared__ float    val0[2][DEG];              // per-row step-0 scores

  const int lane = threadIdx.x;
  const int half = lane >> 5;
  const int hl   = lane & 31;
  const int bid  = blockIdx.x;
  const int r    = bid + half * (BB / 2);
  const int self = train_index[r];               // per-half-uniform
  const uint32_t rN = (uint32_t)(r * N);
  const uint32_t lowerH = (1u << hl) - 1u;       // prefix mask within half

  // per-half neighbor row of self: every lane has one entry (DEG == 32)
  const int nbj = neighbors[(size_t)self * DEG + hl];

  {  // clear both rows' comb: 2*NC u32 == NC u64 words
    uint64_t* c8 = reinterpret_cast<uint64_t*>(&comb[0][0]);
    for (int i = lane; i < NC; i += 64) c8[i] = 0ull;
  }

  // step keys: jax.random.split(key(42), 8) partitionable; lane k holds key k.
  // Never written after init (R8 lesson). Shared by both rows.
  uint32_t sk0, sk1;
  threefry2x32(0u, 42u, 0u, (uint32_t)lane, sk0, sk1);

  // ---- step-0 sx: full 64-lane butterfly per row (bit-identical fold) ----
  const float bval = bptr[0];
  const int selfA = __shfl(self, 0);
  const int selfB = __shfl(self, 32);
  const float* frowA = features + (size_t)selfA * D;
  float accA = frowA[lane] * W[lane] + frowA[lane + 64] * W[lane + 64];
  for (int m = 1; m < 64; m <<= 1) accA += __shfl_xor(accA, m);
  const float* frowB = features + (size_t)selfB * D;
  float accB = frowB[lane] * W[lane] + frowB[lane + 64] * W[lane + 64];
  for (int m = 1; m < 64; m <<= 1) accB += __shfl_xor(accB, m);
  const float sx = half ? accB : accA;

  // sy: one neighbor per lane (64 rows gathered across both halves),
  // serial fold order bit-identical to all passing versions.
  float a = 0.0f;
  {
    const float* g  = features + (size_t)nbj * D;
    const float* wy = W + D;
    for (int d = 0; d < D; d += 4) {
      const float4 f = *reinterpret_cast<const float4*>(g + d);
      const float4 w = *reinterpret_cast<const float4*>(wy + d);
      a += f.x * w.x; a += f.y * w.y; a += f.z * w.z; a += f.w * w.w;
    }
  }
  const float sval = fmaxf((sx + a) + bval, 0.0f);

  // build step-0 list {c != self : s_c > 0} per row; dedup via atomicOr
  bool add0 = (nbj != self && sval > 0.0f);
  if (add0) {
    const uint32_t old = atomicOr(&comb[half][cwd(nbj)], cbit(nbj));
    add0 = !(old & cbit(nbj));
  }
  const uint32_t m0 = (uint32_t)(__ballot(add0) >> (half << 5));
  if (add0) {
    const int p = (int)__popc(m0 & lowerH);
    lst[half][p] = nbj; val0[half][p] = sval;
  }
  int cnt = (int)__popc(m0);                     // per-half-uniform
  if (hl == 0) {
    atomicOr(&comb[half][cwd(self)], cbit(self) << 1);   // chosen = self_oh
    if (cnt == 0) {  // pre-scan fallback mutates the carry: candi = self_oh
      lst[half][0] = self; val0[half][0] = 1.0f;
      atomicOr(&comb[half][cwd(self)], cbit(self));
    }
  }
  if (cnt == 0) cnt = 1;

  // zombies: chosen nodes retained via adjacency (rare); per-half registers.
  int zom0 = 0, zom1 = 0, zom2 = 0, zom3 = 0, zmask = 0;
  uint32_t hiP = 0u, loP = 0u;  // pipelined next-step argmax partials (per lane)

  for (int k = 0; k < T; ++k) {
    // ---- per-half argmax: hi = sort key, lo = (0x7FFFFF - c)<<9 | pos ----
    uint32_t hi, lo;
    if (k == 0) {  // scored: v = log(s) + gumbel, exact f32 pipeline (cnt<=32)
      const uint32_t kk0 = (uint32_t)__builtin_amdgcn_readlane((int)sk0, 0);
      const uint32_t kk1 = (uint32_t)__builtin_amdgcn_readlane((int)sk1, 0);
      hi = 0u; lo = 0u;
      if (hl < cnt) {
        const int c = lst[half][hl];
        const float v = (float)log((double)val0[half][hl])
                      + gumbel_f32(rbits(kk0, kk1, rN + (uint32_t)c));
        hi = f2ord(v); lo = ((0x7FFFFFu - (uint32_t)c) << 9) | (uint32_t)hl;
      }
    } else {
      hi = hiP; lo = loP;  // precomputed during step k-1's nb shadow
    }
    wave_max64_half(hi, lo, half);
    const bool haveList = (cnt > 0);             // per-half-uniform
    const int nn  = haveList ? (int)(0x7FFFFFu - (lo >> 9)) : self;
    const int pos = (int)(lo & 0x1FFu);

    if (hl == 0) out[r * (T + 1) + k + 1] = nn;  // lanes 0 and 32, concurrent
    if (k == T - 1) break;   // lists are dead after the last draw

    // both rows' dependent neighbor loads issue in the SAME instruction;
    // each half's latency hides under the other's VALU work below.
    const int nb = neighbors[(size_t)nn * DEG + hl];

    if (hl == 0) atomicOr(&comb[half][cwd(nn)], cbit(nn) << 1);  // chosen |= nn

    float v0f = 1.0f;
    if (k == 0 && haveList) v0f = val0[half][pos];  // broadcast read per half
    int last = 0;
    if (haveList) last = lst[half][cnt - 1];

    // speculative O(1) removal of nn (re-appended below iff stay)
    if (haveList) {
      if (pos != cnt - 1 && hl == 0) lst[half][pos] = last;
      --cnt;
    }

    const uint32_t nk0 = (uint32_t)__builtin_amdgcn_readlane((int)sk0, k + 1);
    const uint32_t nk1 = (uint32_t)__builtin_amdgcn_readlane((int)sk1, k + 1);

    // pipelined survivor scan for step k+1 — runs in the nb-load shadow
    hiP = 0u; loP = 0u;
    for (int i = hl; i < cnt; i += 32) {
      const int c = lst[half][i];
      const uint32_t h = rbits(nk0, nk1, rN + (uint32_t)c) >> 9;
      const uint32_t l = ((0x7FFFFFu - (uint32_t)c) << 9) | (uint32_t)i;
      if (h > hiP || (h == hiP && l > loP)) { hiP = h; loP = l; }
    }

    // ---- nb-dependent resolution (vmcnt wait lands here) ----
    const bool adNN = ((uint32_t)(__ballot(nb == nn) >> (half << 5))) != 0u;
    const bool wasZ = ((zmask & 1) && zom0 == nn) || ((zmask & 2) && zom1 == nn) ||
                      ((zmask & 4) && zom2 == nn) || ((zmask & 8) && zom3 == nn);
    const bool stay = haveList &&
        ((k == 0) ? (((v0f - 1.0f) + (adNN ? 1.0f : 0.0f)) > 0.0f) : adNN);

    if (stay) {  // rare: re-append nn; track as zombie; merge its key
      if (hl == 0) lst[half][cnt] = nn;
      const int posN = cnt; ++cnt;
      if (!wasZ) {
        if      (!(zmask & 1)) { zom0 = nn; zmask |= 1; }
        else if (!(zmask & 2)) { zom1 = nn; zmask |= 2; }
        else if (!(zmask & 4)) { zom2 = nn; zmask |= 4; }
        else                   { zom3 = nn; zmask |= 8; }
      }
      const uint32_t h = rbits(nk0, nk1, rN + (uint32_t)nn) >> 9;
      const uint32_t l = ((0x7FFFFFu - (uint32_t)nn) << 9) | (uint32_t)posN;
      if (h > hiP || (h == hiP && l > loP)) { hiP = h; loP = l; }
    } else if (wasZ) {  // nn was a zombie and now leaves for good
      if ((zmask & 1) && zom0 == nn) zmask &= ~1;
      else if ((zmask & 2) && zom1 == nn) zmask &= ~2;
      else if ((zmask & 4) && zom2 == nn) zmask &= ~4;
      else if ((zmask & 8) && zom3 == nn) zmask &= ~8;
    }

    // zombie retests (rare, per-half skip): z stays iff z in nb(nn)
    bool zdrop = false;
    if (zmask) {
#define ZTEST(BIT, Z) \
      if ((zmask & BIT) && Z != nn) { \
        if (((uint32_t)(__ballot(nb == Z) >> (half << 5))) == 0u) { \
          int pz = -1; \
          for (int i = hl; i < cnt; i += 32) if (lst[half][i] == Z) pz = i; \
          const uint32_t fz = (uint32_t)(__ballot(pz >= 0) >> (half << 5)); \
          const int sz = (half << 5) + (__ffs(fz) - 1); \
          pz = __shfl(pz, sz); \
          const int lastz = lst[half][cnt - 1]; \
          if (pz != cnt - 1 && hl == 0) lst[half][pz] = lastz; \
          --cnt; zmask &= ~BIT; zdrop = true; \
        } \
      }
      ZTEST(1, zom0) ZTEST(2, zom1) ZTEST(4, zom2) ZTEST(8, zom3)
#undef ZTEST
    }
    if (zdrop) {  // rare: positions shifted — recompute this half's partials
      hiP = 0u; loP = 0u;
      for (int i = hl; i < cnt; i += 32) {
        const int c = lst[half][i];
        const uint32_t h = rbits(nk0, nk1, rN + (uint32_t)c) >> 9;
        const uint32_t l = ((0x7FFFFFu - (uint32_t)c) << 9) | (uint32_t)i;
        if (h > hiP || (h == hiP && l > loP)) { hiP = h; loP = l; }
      }
    }

    // (b) fresh adj members — add-key threefry before the atomic round-trip;
    // ONE atomicOr old-word tests cand AND chosen bits (nn's chosen set above,
    // same-wave DS ops complete in order).
    const uint32_t hN = rbits(nk0, nk1, rN + (uint32_t)nb) >> 9;
    const uint32_t old = atomicOr(&comb[half][cwd(nb)], cbit(nb));
    const bool added = !(old & (cbit(nb) | (cbit(nb) << 1)));
    const uint32_t ma = (uint32_t)(__ballot(added) >> (half << 5));
    const int mypos = cnt + (int)__popc(ma & lowerH);
    if (added) {
      lst[half][mypos] = nb;
      const uint32_t l = ((0x7FFFFFu - (uint32_t)nb) << 9) | (uint32_t)mypos;
      if (hN > hiP || (hN == hiP && l > loP)) { hiP = hN; loP = l; }
    }
    cnt += (int)__popc(ma);
  }
  if (hl == 0) out[r * (T + 1)] = self;
}

}  // namespace

extern "C" void kernel_launch(void* const* d_in, const int* in_sizes, int n_in,
                              void* d_out, int out_size, void* d_ws, size_t ws_size,
                              hipStream_t stream) {
  const float* features  = (const float*)d_in[0];
  const float* W         = (const float*)d_in[1];
  const float* b         = (const float*)d_in[2];
  const int*   neighbors = (const int*)d_in[3];
  const int*   tindex    = (const int*)d_in[4];
  int* out = (int*)d_out;

  hipLaunchKernelGGL(walk_kernel, dim3(BB / 2), dim3(64), 0, stream,
                     features, W, b, neighbors, tindex, out);
}

// Round 13
// 25.302 us; speedup vs baseline: 1.0403x; 1.0403x over previous
//
#include <hip/hip_runtime.h>
#include <cstdint>

namespace {

constexpr int N     = 20000;   // nodes
constexpr int D     = 128;     // feature dim
constexpr int DEG   = 32;      // neighbors per node
constexpr int BB    = 1024;    // batch
constexpr int T     = 8;       // walk_times
constexpr int NC    = (N + 15) / 16;  // 1250 combined-mask words (2 bits/node)
constexpr int MAXC  = 320;     // 5 slots x 64 lanes (true max ~292)
constexpr int SLOTS = 5;

__device__ __forceinline__ uint32_t rotl32(uint32_t x, int n) {
  return (x << n) | (x >> (32 - n));
}

// Threefry-2x32, 20 rounds (Random123 / JAX threefry2x32_p).
__device__ __forceinline__ void threefry2x32(uint32_t k0, uint32_t k1,
                                             uint32_t x0, uint32_t x1,
                                             uint32_t& o0, uint32_t& o1) {
  const uint32_t ks2 = k0 ^ k1 ^ 0x1BD11BDAu;
  x0 += k0; x1 += k1;
#define TF_ROUND(r) { x0 += x1; x1 = rotl32(x1, (r)); x1 ^= x0; }
  TF_ROUND(13) TF_ROUND(15) TF_ROUND(26) TF_ROUND(6)
  x0 += k1;  x1 += ks2 + 1u;
  TF_ROUND(17) TF_ROUND(29) TF_ROUND(16) TF_ROUND(24)
  x0 += ks2; x1 += k0 + 2u;
  TF_ROUND(13) TF_ROUND(15) TF_ROUND(26) TF_ROUND(6)
  x0 += k0;  x1 += k1 + 3u;
  TF_ROUND(17) TF_ROUND(29) TF_ROUND(16) TF_ROUND(24)
  x0 += k1;  x1 += ks2 + 4u;
  TF_ROUND(13) TF_ROUND(15) TF_ROUND(26) TF_ROUND(6)
  x0 += ks2; x1 += k0 + 5u;
#undef TF_ROUND
  o0 = x0; o1 = x1;
}

__device__ __forceinline__ uint32_t rbits(uint32_t k0, uint32_t k1, uint32_t j) {
  uint32_t o0, o1;
  threefry2x32(k0, k1, 0u, j, o0, o1);
  return o0 ^ o1;
}

// Exact jax.random.gumbel f32 pipeline (step 0 only).
__device__ __forceinline__ float gumbel_f32(uint32_t bits) {
  const uint32_t mant = bits >> 9;
  const float u = (mant == 0u) ? 1.17549435e-38f
                               : (__uint_as_float(0x3F800000u | mant) - 1.0f);
  const float inner = -(float)log((double)u);
  return -(float)log((double)inner);
}

// Monotone f32 -> u32 map (finite floats).
__device__ __forceinline__ uint32_t f2ord(float f) {
  const uint32_t b = __float_as_uint(f);
  return (b & 0x80000000u) ? ~b : (b | 0x80000000u);
}

template <int CTRL>
__device__ __forceinline__ uint32_t dppmov(uint32_t v) {
  return (uint32_t)__builtin_amdgcn_update_dpp((int)v, (int)v, CTRL, 0xF, 0xF, false);
}

// Exact wave64 max of packed (hi:lo) u64; result broadcast to all lanes.
__device__ __forceinline__ void wave_max64(uint32_t& hi, uint32_t& lo) {
#define RL(CTRL) { const uint32_t oh = dppmov<CTRL>(hi), ol = dppmov<CTRL>(lo); \
    if (oh > hi || (oh == hi && ol > lo)) { hi = oh; lo = ol; } }
  RL(0x111) RL(0x112) RL(0x114) RL(0x118) RL(0x142) RL(0x143)
#undef RL
  hi = (uint32_t)__builtin_amdgcn_readlane((int)hi, 63);
  lo = (uint32_t)__builtin_amdgcn_readlane((int)lo, 63);
}

// combined mask helpers: word holds 16 nodes x {cand bit, chosen bit}
__device__ __forceinline__ uint32_t cwd(int n)  { return (uint32_t)n >> 4; }
__device__ __forceinline__ uint32_t cbit(int n) { return 1u << (((uint32_t)n & 15u) << 1); }
// chosen bit = cbit << 1

// Register-resident list: lane holds entries {s*64+lane} in c0..c4.
// All slot indexing is compile-time (unrolled) or a uniform scalar 5-way
// branch (rule #20: no runtime-indexed register arrays).
#define GETC(S) ((S)==0?c0:(S)==1?c1:(S)==2?c2:(S)==3?c3:c4)

__global__ __launch_bounds__(64)
void walk_kernel(const float* __restrict__ features,
                 const float* __restrict__ W,
                 const float* __restrict__ bptr,
                 const int*   __restrict__ neighbors,
                 const int*   __restrict__ train_index,
                 int* __restrict__ out)
{
  __shared__ __align__(8) uint32_t comb[NC];  // bit0(cand)/bit1(chosen) per node
  __shared__ int      stage[MAXC];  // append mailbox ONLY (scans never read it)
  __shared__ float    val0[DEG];    // step-0 scores (val==1 afterwards)

  const int lane = threadIdx.x;
  const int r    = blockIdx.x;
  const int self = train_index[r];
  const uint32_t rN = (uint32_t)(r * N);
  const uint64_t lower = (1ULL << lane) - 1ULL;

  int c0 = 0, c1 = 0, c2 = 0, c3 = 0, c4 = 0;   // the candidate list

  int nbj = -1;
  if (lane < DEG) nbj = neighbors[(size_t)self * DEG + lane];

  {  // clear comb (64-bit stores)
    uint64_t* c8 = reinterpret_cast<uint64_t*>(comb);
    for (int i = lane; i < NC / 2; i += 64) c8[i] = 0ull;
  }

  // step keys: jax.random.split(key(42), 8) partitionable; lane k holds key k.
  // NEVER written after init (R8 lesson).
  uint32_t sk0, sk1;
  threefry2x32(0u, 42u, 0u, (uint32_t)lane, sk0, sk1);

  // ---- step-0 scores (fold order bit-identical to passing versions) ----
  const float bval = bptr[0];
  const float* frow = features + (size_t)self * D;
  float acc = frow[lane] * W[lane] + frow[lane + 64] * W[lane + 64];
  for (int m = 1; m < 64; m <<= 1) acc += __shfl_xor(acc, m);
  const float sx = acc;

  float sval = 0.0f;
  if (lane < DEG) {
    const float* g  = features + (size_t)nbj * D;
    const float* wy = W + D;
    float a = 0.0f;
    for (int d = 0; d < D; d += 4) {
      const float4 f = *reinterpret_cast<const float4*>(g + d);
      const float4 w = *reinterpret_cast<const float4*>(wy + d);
      a += f.x * w.x; a += f.y * w.y; a += f.z * w.z; a += f.w * w.w;
    }
    sval = fmaxf((sx + a) + bval, 0.0f);
  }

  // build step-0 list {c != self : s_c > 0}; dedup via single atomicOr.
  // Entries land in slot 0 via the stage mailbox (same-wave DS in-order).
  bool add0 = false;
  if (lane < DEG && nbj != self && sval > 0.0f) {
    const uint32_t old = atomicOr(&comb[cwd(nbj)], cbit(nbj));
    add0 = !(old & cbit(nbj));
  }
  const uint64_t m0 = __ballot(add0);
  if (add0) {
    const int p = (int)__popcll(m0 & lower);
    stage[p] = nbj; val0[p] = sval;
  }
  int cnt = (int)__popcll(m0);
  if (lane == 0) {
    atomicOr(&comb[cwd(self)], cbit(self) << 1);   // chosen = self_oh
    if (cnt == 0) {  // pre-scan fallback mutates the carry: candi = self_oh
      val0[0] = 1.0f;
      atomicOr(&comb[cwd(self)], cbit(self));
    }
  }
  if (cnt == 0) {
    if (lane == 0) c0 = self;
    cnt = 1;
  } else if (lane < cnt) {
    c0 = stage[lane];   // reads the just-written mailbox (same-wave order)
  }

  // zombies: chosen nodes retained via adjacency (rare). Static slots.
  int zom0 = 0, zom1 = 0, zom2 = 0, zom3 = 0, zmask = 0;
  uint32_t hiP = 0u, loP = 0u;  // pipelined next-step argmax partials

  for (int k = 0; k < T; ++k) {
    // ---- argmax: hi = sort key, lo = (0x7FFFFF - c)<<9 | pos ----
    uint32_t hi, lo;
    if (k == 0) {  // scored: v = log(s) + gumbel, exact f32 pipeline (cnt<=32)
      const uint32_t kk0 = (uint32_t)__builtin_amdgcn_readlane((int)sk0, 0);
      const uint32_t kk1 = (uint32_t)__builtin_amdgcn_readlane((int)sk1, 0);
      hi = 0u; lo = 0u;
      if (lane < cnt) {
        const int c = c0;
        const float v = (float)log((double)val0[lane])
                      + gumbel_f32(rbits(kk0, kk1, rN + (uint32_t)c));
        hi = f2ord(v); lo = ((0x7FFFFFu - (uint32_t)c) << 9) | (uint32_t)lane;
      }
    } else {
      hi = hiP; lo = loP;  // precomputed during step k-1's nb shadow
    }
    wave_max64(hi, lo);
    const bool haveList = (cnt > 0);
    const int nn  = haveList ? (int)(0x7FFFFFu - (lo >> 9)) : self;
    const int pos = (int)(lo & 0x1FFu);

    if (lane == 0) out[r * (T + 1) + k + 1] = nn;
    if (k == T - 1) break;   // list is dead after the last draw

    // dependent neighbor-row load; overlaps everything until first use of nb
    int nb = -1;
    if (lane < DEG) nb = neighbors[(size_t)nn * DEG + lane];

    if (lane == 0) atomicOr(&comb[cwd(nn)], cbit(nn) << 1);  // chosen |= nn

    float v0f = 1.0f;
    if (k == 0 && haveList) v0f = val0[pos];  // broadcast read (pre-removal)

    // O(1) removal of nn: swap last entry into pos — pure VALU now.
    if (haveList) {
      const int li = cnt - 1;
      int last;
      { const int ls = li >> 6, ll = li & 63;
        if      (ls == 0) last = __builtin_amdgcn_readlane(c0, ll);
        else if (ls == 1) last = __builtin_amdgcn_readlane(c1, ll);
        else if (ls == 2) last = __builtin_amdgcn_readlane(c2, ll);
        else if (ls == 3) last = __builtin_amdgcn_readlane(c3, ll);
        else              last = __builtin_amdgcn_readlane(c4, ll);
      }
      if (pos != li) {
        const int ps = pos >> 6, pl = pos & 63;
        if      (ps == 0) { if (lane == pl) c0 = last; }
        else if (ps == 1) { if (lane == pl) c1 = last; }
        else if (ps == 2) { if (lane == pl) c2 = last; }
        else if (ps == 3) { if (lane == pl) c3 = last; }
        else              { if (lane == pl) c4 = last; }
      }
      --cnt;
    }

    const uint32_t nk0 = (uint32_t)__builtin_amdgcn_readlane((int)sk0, k + 1);
    const uint32_t nk1 = (uint32_t)__builtin_amdgcn_readlane((int)sk1, k + 1);

    // survivor scan for step k+1 over the post-removal register list —
    // pure VALU, runs entirely in the nb-load shadow.
    hiP = 0u; loP = 0u;
#pragma unroll
    for (int s = 0; s < SLOTS; ++s) {
      const int idx = s * 64 + lane;
      if (idx < cnt) {
        const int c = GETC(s);
        const uint32_t h = rbits(nk0, nk1, rN + (uint32_t)c) >> 9;
        const uint32_t l = ((0x7FFFFFu - (uint32_t)c) << 9) | (uint32_t)idx;
        if (h > hiP || (h == hiP && l > loP)) { hiP = h; loP = l; }
      }
    }

    // ---- nb-dependent resolution (vmcnt wait lands here) ----
    const bool adNN = __any(nb == nn);
    const bool wasZ = ((zmask & 1) && zom0 == nn) || ((zmask & 2) && zom1 == nn) ||
                      ((zmask & 4) && zom2 == nn) || ((zmask & 8) && zom3 == nn);
    const bool stay = haveList &&
        ((k == 0) ? (((v0f - 1.0f) + (adNN ? 1.0f : 0.0f)) > 0.0f) : adNN);

    if (stay) {  // rare: re-append nn (uniform value — pure VALU); zombie-track
      const int posN = cnt;
      { const int ps = posN >> 6, pl = posN & 63;
        if      (ps == 0) { if (lane == pl) c0 = nn; }
        else if (ps == 1) { if (lane == pl) c1 = nn; }
        else if (ps == 2) { if (lane == pl) c2 = nn; }
        else if (ps == 3) { if (lane == pl) c3 = nn; }
        else              { if (lane == pl) c4 = nn; }
      }
      ++cnt;
      if (!wasZ) {
        if      (!(zmask & 1)) { zom0 = nn; zmask |= 1; }
        else if (!(zmask & 2)) { zom1 = nn; zmask |= 2; }
        else if (!(zmask & 4)) { zom2 = nn; zmask |= 4; }
        else                   { zom3 = nn; zmask |= 8; }
      }
      const uint32_t h = rbits(nk0, nk1, rN + (uint32_t)nn) >> 9;
      const uint32_t l = ((0x7FFFFFu - (uint32_t)nn) << 9) | (uint32_t)posN;
      if (h > hiP || (h == hiP && l > loP)) { hiP = h; loP = l; }
    } else if (wasZ) {  // nn was a zombie and now leaves for good
      if ((zmask & 1) && zom0 == nn) zmask &= ~1;
      else if ((zmask & 2) && zom1 == nn) zmask &= ~2;
      else if ((zmask & 4) && zom2 == nn) zmask &= ~4;
      else if ((zmask & 8) && zom3 == nn) zmask &= ~8;
    }

    // zombie retests (rare, wave-uniform skip): z stays iff z in nb(nn).
    bool zdrop = false;
    if (zmask) {
#define ZTEST(BIT, Z) \
      if ((zmask & BIT) && Z != nn) { \
        if (!__any(nb == Z)) { \
          int pz = -1; \
          if (0 * 64 + lane < cnt && c0 == Z) pz = 0 * 64 + lane; \
          if (1 * 64 + lane < cnt && c1 == Z) pz = 1 * 64 + lane; \
          if (2 * 64 + lane < cnt && c2 == Z) pz = 2 * 64 + lane; \
          if (3 * 64 + lane < cnt && c3 == Z) pz = 3 * 64 + lane; \
          if (4 * 64 + lane < cnt && c4 == Z) pz = 4 * 64 + lane; \
          const uint64_t fz = __ballot(pz >= 0); \
          const int sz = (int)(__ffsll((unsigned long long)fz) - 1); \
          pz = __shfl(pz, sz); \
          const int li = cnt - 1; \
          int lastz; \
          { const int ls = li >> 6, ll = li & 63; \
            if      (ls == 0) lastz = __builtin_amdgcn_readlane(c0, ll); \
            else if (ls == 1) lastz = __builtin_amdgcn_readlane(c1, ll); \
            else if (ls == 2) lastz = __builtin_amdgcn_readlane(c2, ll); \
            else if (ls == 3) lastz = __builtin_amdgcn_readlane(c3, ll); \
            else              lastz = __builtin_amdgcn_readlane(c4, ll); \
          } \
          if (pz != li) { \
            const int ps = pz >> 6, pl = pz & 63; \
            if      (ps == 0) { if (lane == pl) c0 = lastz; } \
            else if (ps == 1) { if (lane == pl) c1 = lastz; } \
            else if (ps == 2) { if (lane == pl) c2 = lastz; } \
            else if (ps == 3) { if (lane == pl) c3 = lastz; } \
            else              { if (lane == pl) c4 = lastz; } \
          } \
          --cnt; zmask &= ~BIT; zdrop = true; \
        } \
      }
      ZTEST(1, zom0) ZTEST(2, zom1) ZTEST(4, zom2) ZTEST(8, zom3)
#undef ZTEST
    }
    if (zdrop) {  // rare: positions shifted — recompute partials (pure VALU)
      hiP = 0u; loP = 0u;
#pragma unroll
      for (int s = 0; s < SLOTS; ++s) {
        const int idx = s * 64 + lane;
        if (idx < cnt) {
          const int c = GETC(s);
          const uint32_t h = rbits(nk0, nk1, rN + (uint32_t)c) >> 9;
          const uint32_t l = ((0x7FFFFFu - (uint32_t)c) << 9) | (uint32_t)idx;
          if (h > hiP || (h == hiP && l > loP)) { hiP = h; loP = l; }
        }
      }
    }

    // (b) fresh adj members — add-key threefry before the atomic round-trip;
    // ONE atomicOr old-word tests cand AND chosen bits. Added values are
    // routed lane->slot via the stage mailbox (write then read, same-wave
    // DS ordering); the read's latency hides before the next step's scan.
    uint32_t hN = 0u;
    if (lane < DEG) hN = rbits(nk0, nk1, rN + (uint32_t)nb) >> 9;
    bool added = false;
    if (lane < DEG) {
      const uint32_t old = atomicOr(&comb[cwd(nb)], cbit(nb));
      added = !(old & (cbit(nb) | (cbit(nb) << 1)));
    }
    const uint64_t ma = __ballot(added);
    const int mypos = cnt + (int)__popcll(ma & lower);
    if (added) {
      stage[mypos] = nb;
      const uint32_t l = ((0x7FFFFFu - (uint32_t)nb) << 9) | (uint32_t)mypos;
      if (hN > hiP || (hN == hiP && l > loP)) { hiP = hN; loP = l; }
    }
    const int cntNew = cnt + (int)__popcll(ma);
    // fill newly-covered register slots from the mailbox (<=1 slot per lane)
#pragma unroll
    for (int s = 0; s < SLOTS; ++s) {
      const int idx = s * 64 + lane;
      if (idx >= cnt && idx < cntNew) {
        const int v = stage[idx];
        if      (s == 0) c0 = v;
        else if (s == 1) c1 = v;
        else if (s == 2) c2 = v;
        else if (s == 3) c3 = v;
        else             c4 = v;
      }
    }
    cnt = cntNew;
  }
  if (lane == 0) out[r * (T + 1)] = self;
}

}  // namespace

extern "C" void kernel_launch(void* const* d_in, const int* in_sizes, int n_in,
                              void* d_out, int out_size, void* d_ws, size_t ws_size,
                              hipStream_t stream) {
  const float* features  = (const float*)d_in[0];
  const float* W         = (const float*)d_in[1];
  const float* b         = (const float*)d_in[2];
  const int*   neighbors = (const int*)d_in[3];
  const int*   tindex    = (const int*)d_in[4];
  int* out = (int*)d_out;

  hipLaunchKernelGGL(walk_kernel, dim3(BB), dim3(64), 0, stream,
                     features, W, b, neighbors, tindex, out);
}

// Round 14
// 21.857 us; speedup vs baseline: 1.2043x; 1.1576x over previous
//
#include <hip/hip_runtime.h>
#include <cstdint>

namespace {

constexpr int N    = 20000;   // nodes
constexpr int D    = 128;     // feature dim
constexpr int DEG  = 32;      // neighbors per node
constexpr int BB   = 1024;    // batch
constexpr int T    = 8;       // walk_times
constexpr int NC   = (N + 15) / 16;  // 1250 combined-mask words (2 bits/node)
constexpr int MAXC = 384;     // list bound (true max ~292)

__device__ __forceinline__ uint32_t rotl32(uint32_t x, int n) {
  return (x << n) | (x >> (32 - n));
}

// Threefry-2x32, 20 rounds (Random123 / JAX threefry2x32_p).
__device__ __forceinline__ void threefry2x32(uint32_t k0, uint32_t k1,
                                             uint32_t x0, uint32_t x1,
                                             uint32_t& o0, uint32_t& o1) {
  const uint32_t ks2 = k0 ^ k1 ^ 0x1BD11BDAu;
  x0 += k0; x1 += k1;
#define TF_ROUND(r) { x0 += x1; x1 = rotl32(x1, (r)); x1 ^= x0; }
  TF_ROUND(13) TF_ROUND(15) TF_ROUND(26) TF_ROUND(6)
  x0 += k1;  x1 += ks2 + 1u;
  TF_ROUND(17) TF_ROUND(29) TF_ROUND(16) TF_ROUND(24)
  x0 += ks2; x1 += k0 + 2u;
  TF_ROUND(13) TF_ROUND(15) TF_ROUND(26) TF_ROUND(6)
  x0 += k0;  x1 += k1 + 3u;
  TF_ROUND(17) TF_ROUND(29) TF_ROUND(16) TF_ROUND(24)
  x0 += k1;  x1 += ks2 + 4u;
  TF_ROUND(13) TF_ROUND(15) TF_ROUND(26) TF_ROUND(6)
  x0 += ks2; x1 += k0 + 5u;
#undef TF_ROUND
  o0 = x0; o1 = x1;
}

__device__ __forceinline__ uint32_t rbits(uint32_t k0, uint32_t k1, uint32_t j) {
  uint32_t o0, o1;
  threefry2x32(k0, k1, 0u, j, o0, o1);
  return o0 ^ o1;
}

// Exact jax.random.gumbel f32 pipeline (step 0 only).
__device__ __forceinline__ float gumbel_f32(uint32_t bits) {
  const uint32_t mant = bits >> 9;
  const float u = (mant == 0u) ? 1.17549435e-38f
                               : (__uint_as_float(0x3F800000u | mant) - 1.0f);
  const float inner = -(float)log((double)u);
  return -(float)log((double)inner);
}

// Monotone f32 -> u32 map (finite floats).
__device__ __forceinline__ uint32_t f2ord(float f) {
  const uint32_t b = __float_as_uint(f);
  return (b & 0x80000000u) ? ~b : (b | 0x80000000u);
}

template <int CTRL>
__device__ __forceinline__ uint32_t dppmov(uint32_t v) {
  return (uint32_t)__builtin_amdgcn_update_dpp((int)v, (int)v, CTRL, 0xF, 0xF, false);
}

// Exact wave64 lexicographic argmax of (hi, lo), broadcast to all lanes.
// Fast path: 6-level DPP max on hi only (half the dependent ops of the old
// dual max), then ballot picks the tied lanes and readlane fetches the
// payload. Multi-lane hi-ties (rare) resolve by max lo over the tied set —
// identical result to the old wave_max64 (max hi, then max lo).
__device__ __forceinline__ void wave_argmax(uint32_t& hi, uint32_t& lo) {
  uint32_t km = hi;
#define RM(CTRL) { const uint32_t o = dppmov<CTRL>(km); if (o > km) km = o; }
  RM(0x111) RM(0x112) RM(0x114) RM(0x118) RM(0x142) RM(0x143)
#undef RM
  km = (uint32_t)__builtin_amdgcn_readlane((int)km, 63);
  uint64_t m = __ballot(hi == km);
  const int l0 = (int)(__ffsll((unsigned long long)m) - 1);
  uint32_t best = (uint32_t)__builtin_amdgcn_readlane((int)lo, l0);
  m &= m - 1;
  while (m) {  // rare: hi tied across lanes -> take max payload (exact)
    const int l = (int)(__ffsll((unsigned long long)m) - 1);
    const uint32_t lv = (uint32_t)__builtin_amdgcn_readlane((int)lo, l);
    if (lv > best) best = lv;
    m &= m - 1;
  }
  hi = km; lo = best;
}

// combined mask helpers: word holds 16 nodes x {cand bit, chosen bit}
__device__ __forceinline__ uint32_t cwd(int n)  { return (uint32_t)n >> 4; }
__device__ __forceinline__ uint32_t cbit(int n) { return 1u << (((uint32_t)n & 15u) << 1); }
// chosen bit = cbit << 1

__global__ __launch_bounds__(64)
void walk_kernel(const float* __restrict__ features,
                 const float* __restrict__ W,
                 const float* __restrict__ bptr,
                 const int*   __restrict__ neighbors,
                 const int*   __restrict__ train_index,
                 int* __restrict__ out)
{
  __shared__ uint32_t comb[NC];   // bit0(cand)/bit1(chosen) per node
  __shared__ int      lst[MAXC];  // in-place candidate list
  __shared__ float    val0[DEG];  // step-0 scores (val==1 afterwards)

  const int lane = threadIdx.x;
  const int r    = blockIdx.x;
  const int self = train_index[r];
  const uint32_t rN = (uint32_t)(r * N);
  const uint64_t lower = (1ULL << lane) - 1ULL;

  int nbj = -1;
  if (lane < DEG) nbj = neighbors[(size_t)self * DEG + lane];

  {  // clear comb (64-bit stores)
    uint64_t* c8 = reinterpret_cast<uint64_t*>(comb);
    for (int i = lane; i < NC / 2; i += 64) c8[i] = 0ull;
  }

  // step keys: jax.random.split(key(42), 8) partitionable; lane k holds key k.
  // NEVER written after init (R8's bug: hidden sk0 assignment).
  uint32_t sk0, sk1;
  threefry2x32(0u, 42u, 0u, (uint32_t)lane, sk0, sk1);

  // ---- step-0 scores (fold order bit-identical to passing versions) ----
  const float bval = bptr[0];
  const float* frow = features + (size_t)self * D;
  float acc = frow[lane] * W[lane] + frow[lane + 64] * W[lane + 64];
  for (int m = 1; m < 64; m <<= 1) acc += __shfl_xor(acc, m);
  const float sx = acc;

  float sval = 0.0f;
  if (lane < DEG) {
    const float* g  = features + (size_t)nbj * D;
    const float* wy = W + D;
    float a = 0.0f;
    for (int d = 0; d < D; d += 4) {
      const float4 f = *reinterpret_cast<const float4*>(g + d);
      const float4 w = *reinterpret_cast<const float4*>(wy + d);
      a += f.x * w.x; a += f.y * w.y; a += f.z * w.z; a += f.w * w.w;
    }
    sval = fmaxf((sx + a) + bval, 0.0f);
  }

  // build step-0 list {c != self : s_c > 0}; dedup via single atomicOr
  bool add0 = false;
  if (lane < DEG && nbj != self && sval > 0.0f) {
    const uint32_t old = atomicOr(&comb[cwd(nbj)], cbit(nbj));
    add0 = !(old & cbit(nbj));
  }
  const uint64_t m0 = __ballot(add0);
  if (add0) {
    const int p = (int)__popcll(m0 & lower);
    lst[p] = nbj; val0[p] = sval;
  }
  int cnt = (int)__popcll(m0);
  if (lane == 0) {
    atomicOr(&comb[cwd(self)], cbit(self) << 1);   // chosen = self_oh
    if (cnt == 0) {  // pre-scan fallback mutates the carry: candi = self_oh
      lst[0] = self; val0[0] = 1.0f;
      atomicOr(&comb[cwd(self)], cbit(self));
    }
  }
  if (cnt == 0) cnt = 1;

  // zombies: chosen nodes retained via adjacency (rare). Static slots (rule #20).
  int zom0 = 0, zom1 = 0, zom2 = 0, zom3 = 0, zmask = 0;
  uint32_t hiP = 0u, loP = 0u;  // pipelined next-step argmax partials

  for (int k = 0; k < T; ++k) {
    // ---- argmax: hi = sort key, lo = (0x7FFFFF - c)<<9 | pos ----
    // (equal key -> max lo -> min c; pos is payload — unique per c, dedup'd list)
    uint32_t hi, lo;
    if (k == 0) {  // scored: v = log(s) + gumbel, exact f32 pipeline (cnt<=32)
      const uint32_t kk0 = (uint32_t)__builtin_amdgcn_readlane((int)sk0, 0);
      const uint32_t kk1 = (uint32_t)__builtin_amdgcn_readlane((int)sk1, 0);
      hi = 0u; lo = 0u;
      if (lane < cnt) {
        const int c = lst[lane];
        const float v = (float)log((double)val0[lane])
                      + gumbel_f32(rbits(kk0, kk1, rN + (uint32_t)c));
        hi = f2ord(v); lo = ((0x7FFFFFu - (uint32_t)c) << 9) | (uint32_t)lane;
      }
    } else {
      hi = hiP; lo = loP;  // precomputed during step k-1's nb shadow
    }
    wave_argmax(hi, lo);
    const bool haveList = (cnt > 0);
    const int nn  = haveList ? (int)(0x7FFFFFu - (lo >> 9)) : self;
    const int pos = (int)(lo & 0x1FFu);

    if (lane == 0) out[r * (T + 1) + k + 1] = nn;
    if (k == T - 1) break;   // list is dead after the last draw

    // dependent neighbor-row load; overlaps everything until first use of nb
    int nb = -1;
    if (lane < DEG) nb = neighbors[(size_t)nn * DEG + lane];

    if (lane == 0) atomicOr(&comb[cwd(nn)], cbit(nn) << 1);  // chosen |= nn

    float v0f = 1.0f;
    if (k == 0 && haveList) v0f = val0[pos];  // broadcast read (pre-removal)

    // speculative O(1) removal of nn (re-appended below iff stay; order moot)
    if (haveList) {
      const int last = lst[cnt - 1];            // broadcast read
      if (pos != cnt - 1 && lane == 0) lst[pos] = last;
      --cnt;
    }

    // next-step keys (SGPR via readlane)
    const uint32_t nk0 = (uint32_t)__builtin_amdgcn_readlane((int)sk0, k + 1);
    const uint32_t nk1 = (uint32_t)__builtin_amdgcn_readlane((int)sk1, k + 1);

    // pipelined partial scan for step k+1 over survivors — runs in nb's shadow
    hiP = 0u; loP = 0u;
    for (int i = lane; i < cnt; i += 64) {
      const int c = lst[i];
      const uint32_t h = rbits(nk0, nk1, rN + (uint32_t)c) >> 9;
      const uint32_t l = ((0x7FFFFFu - (uint32_t)c) << 9) | (uint32_t)i;
      if (h > hiP || (h == hiP && l > loP)) { hiP = h; loP = l; }
    }

    // ---- nb-dependent resolution (vmcnt wait lands here) ----
    const bool adNN = __any(nb == nn);
    const bool wasZ = ((zmask & 1) && zom0 == nn) || ((zmask & 2) && zom1 == nn) ||
                      ((zmask & 4) && zom2 == nn) || ((zmask & 8) && zom3 == nn);
    const bool stay = haveList &&
        ((k == 0) ? (((v0f - 1.0f) + (adNN ? 1.0f : 0.0f)) > 0.0f) : adNN);

    if (stay) {  // rare: re-append nn; track as zombie; merge its key
      if (lane == 0) lst[cnt] = nn;
      const int posN = cnt; ++cnt;
      if (!wasZ) {
        if      (!(zmask & 1)) { zom0 = nn; zmask |= 1; }
        else if (!(zmask & 2)) { zom1 = nn; zmask |= 2; }
        else if (!(zmask & 4)) { zom2 = nn; zmask |= 4; }
        else                   { zom3 = nn; zmask |= 8; }
      }
      const uint32_t h = rbits(nk0, nk1, rN + (uint32_t)nn) >> 9;
      const uint32_t l = ((0x7FFFFFu - (uint32_t)nn) << 9) | (uint32_t)posN;
      if (h > hiP || (h == hiP && l > loP)) { hiP = h; loP = l; }
    } else if (wasZ) {  // nn was a zombie and now leaves for good
      if ((zmask & 1) && zom0 == nn) zmask &= ~1;
      else if ((zmask & 2) && zom1 == nn) zmask &= ~2;
      else if ((zmask & 4) && zom2 == nn) zmask &= ~4;
      else if ((zmask & 8) && zom3 == nn) zmask &= ~8;
    }

    // zombie retests (rare, wave-uniform skip): z stays iff z in nb(nn)
    bool zdrop = false;
    if (zmask) {
#define ZTEST(BIT, Z) \
      if ((zmask & BIT) && Z != nn) { \
        if (!__any(nb == Z)) { \
          int pz = -1; \
          for (int i = lane; i < cnt; i += 64) if (lst[i] == Z) pz = i; \
          const uint64_t fz = __ballot(pz >= 0); \
          const int sz = (int)(__ffsll((unsigned long long)fz) - 1); \
          pz = __shfl(pz, sz); \
          const int lastz = lst[cnt - 1]; \
          if (pz != cnt - 1 && lane == 0) lst[pz] = lastz; \
          --cnt; zmask &= ~BIT; zdrop = true; \
        } \
      }
      ZTEST(1, zom0) ZTEST(2, zom1) ZTEST(4, zom2) ZTEST(8, zom3)
#undef ZTEST
    }
    if (zdrop) {  // rare: partials may reference dropped/moved entries — redo
      hiP = 0u; loP = 0u;
      for (int i = lane; i < cnt; i += 64) {
        const int c = lst[i];
        const uint32_t h = rbits(nk0, nk1, rN + (uint32_t)c) >> 9;
        const uint32_t l = ((0x7FFFFFu - (uint32_t)c) << 9) | (uint32_t)i;
        if (h > hiP || (h == hiP && l > loP)) { hiP = h; loP = l; }
      }
    }

    // (b) fresh adj members — ONE atomic: old word tests cand AND chosen bits.
    // (nn's chosen bit was set above; same-wave DS ops complete in order.)
    bool added = false;
    const int nbv = nb;
    if (lane < DEG) {
      const uint32_t old = atomicOr(&comb[cwd(nbv)], cbit(nbv));
      added = !(old & (cbit(nbv) | (cbit(nbv) << 1)));
    }
    const uint64_t ma = __ballot(added);
    const int mypos = cnt + (int)__popcll(ma & lower);
    if (added) {
      lst[mypos] = nbv;
      const uint32_t h = rbits(nk0, nk1, rN + (uint32_t)nbv) >> 9;
      const uint32_t l = ((0x7FFFFFu - (uint32_t)nbv) << 9) | (uint32_t)mypos;
      if (h > hiP || (h == hiP && l > loP)) { hiP = h; loP = l; }
    }
    cnt += (int)__popcll(ma);
  }
  if (lane == 0) out[r * (T + 1)] = self;
}

}  // namespace

extern "C" void kernel_launch(void* const* d_in, const int* in_sizes, int n_in,
                              void* d_out, int out_size, void* d_ws, size_t ws_size,
                              hipStream_t stream) {
  const float* features  = (const float*)d_in[0];
  const float* W         = (const float*)d_in[1];
  const float* b         = (const float*)d_in[2];
  const int*   neighbors = (const int*)d_in[3];
  const int*   tindex    = (const int*)d_in[4];
  int* out = (int*)d_out;

  hipLaunchKernelGGL(walk_kernel, dim3(BB), dim3(64), 0, stream,
                     features, W, b, neighbors, tindex, out);
}